// Round 22
// baseline (532.818 us; speedup 1.0000x reference)
//
#include <hip/hip_runtime.h>
#include <cstdint>

// ---------------------------------------------------------------------------
// Red-black SOR Laplace solver, persistent kernel. Round 22 = round 21
// (single flag-sync/iter, halo-black recompute, LDS-staged channels) with
// two latency shaves: NTHR 1024->512 (cheaper barriers; all phases <=3
// items/thread) and flag-posted-before-dv-sum (neighbors' wait no longer
// includes our 8-add reduce chain). Numerics byte-identical to r21
// (passed, iters=149): same lists/op order/staged f32 bits, same exact
// fixed-point dv ring, lagged uniform stop at g=t-2.
// Structure per iteration:
//   wait(red flags z+-1,z+-2 >= t-1, || dv-ring poll+stop) -> stage burst
//   (z+-1 full packed halves + z+-2 far entries, regs-then-LDS) -> black
//   own sweep + halo-XB updates (LDS only) -> red own sweep (XB crosses)
//   + inline publish -> flag -> dv reduce + ring post.
// ---------------------------------------------------------------------------

#define NBLK 132
#define NTHR 512
#define NW   (NTHR / 64)

constexpr int NJK   = 66;
constexpr int PLANE = 66 * 66;          // 4356
constexpr int HPL   = PLANE / 2;        // 2178 packed entries per half
constexpr int NI    = 132;
constexpr int CAPL  = 2048;             // max gm per color per plane
constexpr int CAPH  = 768;              // halo cross-set cap (mean ~136)
constexpr int NOUT  = 2 * 64 * 64 * 64; // 524288
// ctrl 128B lines: [0..127] dv rings 0..7 (16 lines each); [128..143]
// startup barrier; [276..407] red flags (276+b).
constexpr int CTRL_U64 = 408 * 16;
constexpr unsigned long long CNT1   = 1ull << 44;
constexpr unsigned long long MASK44 = CNT1 - 1ull;

__global__ void sor_init_ctrl(unsigned long long* ctrl) {
  for (int i = threadIdx.x; i < CTRL_U64; i += blockDim.x) ctrl[i] = 0ull;
}

__device__ __forceinline__ float cloadf(const float* p) {
  return __hip_atomic_load(p, __ATOMIC_RELAXED, __HIP_MEMORY_SCOPE_AGENT);
}
__device__ __forceinline__ void cstoref(float* p, float v) {
  __hip_atomic_store(p, v, __ATOMIC_RELAXED, __HIP_MEMORY_SCOPE_AGENT);
}
__device__ __forceinline__ unsigned long long cloadu(const unsigned long long* p) {
  return __hip_atomic_load(p, __ATOMIC_RELAXED, __HIP_MEMORY_SCOPE_AGENT);
}
__device__ __forceinline__ void cstoreu(unsigned long long* p, unsigned long long v) {
  __hip_atomic_store(p, v, __ATOMIC_RELAXED, __HIP_MEMORY_SCOPE_AGENT);
}

// padded flat coords -> original image flat index, or -1 if pad voxel
__device__ __forceinline__ int pad_label_idx(int ii, int jj, int kk) {
  int b  = (ii >= 66) ? 1 : 0;
  int pz = ii - 66 * b;
  if (pz < 1 || pz > 64 || jj < 1 || jj > 64 || kk < 1 || kk > 64) return -1;
  return ((b * 64 + (pz - 1)) * 64 + (jj - 1)) * 64 + (kk - 1);
}

__global__ __launch_bounds__(NTHR, 1)
void sor_main(const float* __restrict__ img,
              float* __restrict__ pr0, float* __restrict__ pr1,
              unsigned long long* __restrict__ ctrl,
              float* __restrict__ out) {
  __shared__ double P1[PLANE];                 // own plane, f64
  __shared__ double XBm[CAPH], XBp[CAPH];      // halo-black states z-1 / z+1
  __shared__ unsigned short hm[CAPH], hp[CAPH];
  __shared__ unsigned short tmpm[PLANE], tmpp[PLANE];  // o -> halo rank
  __shared__ unsigned lsB[CAPL], lsR[CAPL];    // o | (c<<16)
  __shared__ unsigned auxR[CAPL];              // im | (ip<<16)
  __shared__ float CM[HPL], CP[HPL];           // staged red halves z-1 / z+1
  __shared__ float FM[CAPH], FP[CAPH];         // staged far entries z-2 / z+2
  __shared__ unsigned wsum[NW], woff[NW];
  __shared__ unsigned tot;
  __shared__ double redw[NW];
  __shared__ unsigned long long prevs[8];
  __shared__ double sh_dv;

  const int tid = threadIdx.x, bid = blockIdx.x;
  const int lane = tid & 63, wid = tid >> 6;
  const int z = bid;

  // ---- init own plane + XB + rank maps ----
  for (int o = tid; o < PLANE; o += NTHR) {
    int j = o / NJK, k = o - j * NJK;
    int li = pad_label_idx(z, j, k);
    float L = (li >= 0) ? img[li] : 0.0f;
    P1[o] = (L == 3.0f) ? 1.0 : 0.0;
    tmpm[o] = 0xFFFFu; tmpp[o] = 0xFFFFu;
  }
  for (int i = tid; i < CAPH; i += NTHR) { XBm[i] = 0.0; XBp[i] = 0.0; }
  if (tid < 8) prevs[tid] = 0ull;
  __syncthreads();

  const int CH = (PLANE + NTHR - 1) / NTHR;
  int cntB = 0, cntR = 0, nHm = 0, nHp = 0;

  // ---- pass 0: black list (o | c<<16) ----
  {
    int c0 = tid * CH, c1 = (c0 + CH < PLANE) ? (c0 + CH) : PLANE;
    unsigned cnt = 0;
    for (int o = c0; o < c1; ++o) {
      int j = o / NJK, k = o - j * NJK;
      if (((z + j + k) & 1) != 0) continue;
      int li = pad_label_idx(z, j, k);
      if (((li >= 0) ? img[li] : 0.0f) == 1.0f) cnt++;
    }
    unsigned incl = cnt;
    #pragma unroll
    for (int m = 1; m < 64; m <<= 1) {
      unsigned t = __shfl_up(incl, m, 64);
      if (lane >= m) incl += t;
    }
    __syncthreads();
    if (lane == 63) wsum[wid] = incl;
    __syncthreads();
    if (tid == 0) {
      unsigned a = 0;
      for (int w = 0; w < NW; ++w) { unsigned c = wsum[w]; woff[w] = a; a += c; }
      tot = a;
    }
    __syncthreads();
    unsigned p = (incl - cnt) + woff[wid];
    for (int o = c0; o < c1; ++o) {
      int j = o / NJK, k = o - j * NJK;
      if (((z + j + k) & 1) != 0) continue;
      int li = pad_label_idx(z, j, k);
      if (((li >= 0) ? img[li] : 0.0f) == 1.0f)
        lsB[p++] = (unsigned)o | ((unsigned)(o >> 1) << 16);
    }
    __syncthreads();
    cntB = (int)tot;
    __syncthreads();
  }

  // ---- passes 1/2: halo cross lists per direction (red-in-z, gm both) ----
  for (int dir = 0; dir < 2; ++dir) {
    const int zx = (dir == 0) ? (z - 1) : (z + 1);
    unsigned short* hl  = (dir == 0) ? hm : hp;
    unsigned short* tmp = (dir == 0) ? tmpm : tmpp;
    int c0 = tid * CH, c1 = (c0 + CH < PLANE) ? (c0 + CH) : PLANE;
    unsigned cnt = 0;
    for (int o = c0; o < c1; ++o) {
      int j = o / NJK, k = o - j * NJK;
      if (((z + j + k) & 1) != 1) continue;
      int li = pad_label_idx(z, j, k);
      if (((li >= 0) ? img[li] : 0.0f) != 1.0f) continue;
      int lx = pad_label_idx(zx, j, k);
      if (((lx >= 0) ? img[lx] : 0.0f) == 1.0f) cnt++;
    }
    unsigned incl = cnt;
    #pragma unroll
    for (int m = 1; m < 64; m <<= 1) {
      unsigned t = __shfl_up(incl, m, 64);
      if (lane >= m) incl += t;
    }
    __syncthreads();
    if (lane == 63) wsum[wid] = incl;
    __syncthreads();
    if (tid == 0) {
      unsigned a = 0;
      for (int w = 0; w < NW; ++w) { unsigned c = wsum[w]; woff[w] = a; a += c; }
      tot = a;
    }
    __syncthreads();
    unsigned p = (incl - cnt) + woff[wid];
    for (int o = c0; o < c1; ++o) {
      int j = o / NJK, k = o - j * NJK;
      if (((z + j + k) & 1) != 1) continue;
      int li = pad_label_idx(z, j, k);
      if (((li >= 0) ? img[li] : 0.0f) != 1.0f) continue;
      int lx = pad_label_idx(zx, j, k);
      if (((lx >= 0) ? img[lx] : 0.0f) == 1.0f) {
        hl[p] = (unsigned short)o;
        tmp[o] = (unsigned short)p;
        p++;
      }
    }
    __syncthreads();
    if (dir == 0) nHm = (int)tot; else nHp = (int)tot;
    __syncthreads();
  }

  // ---- pass 3: red list + aux codes ----
  {
    int c0 = tid * CH, c1 = (c0 + CH < PLANE) ? (c0 + CH) : PLANE;
    unsigned cnt = 0;
    for (int o = c0; o < c1; ++o) {
      int j = o / NJK, k = o - j * NJK;
      if (((z + j + k) & 1) != 1) continue;
      int li = pad_label_idx(z, j, k);
      if (((li >= 0) ? img[li] : 0.0f) == 1.0f) cnt++;
    }
    unsigned incl = cnt;
    #pragma unroll
    for (int m = 1; m < 64; m <<= 1) {
      unsigned t = __shfl_up(incl, m, 64);
      if (lane >= m) incl += t;
    }
    __syncthreads();
    if (lane == 63) wsum[wid] = incl;
    __syncthreads();
    if (tid == 0) {
      unsigned a = 0;
      for (int w = 0; w < NW; ++w) { unsigned c = wsum[w]; woff[w] = a; a += c; }
      tot = a;
    }
    __syncthreads();
    unsigned p = (incl - cnt) + woff[wid];
    for (int o = c0; o < c1; ++o) {
      int j = o / NJK, k = o - j * NJK;
      if (((z + j + k) & 1) != 1) continue;
      int li = pad_label_idx(z, j, k);
      if (((li >= 0) ? img[li] : 0.0f) != 1.0f) continue;
      int lm = pad_label_idx(z - 1, j, k);
      float Lm = (lm >= 0) ? img[lm] : 0.0f;
      int lp = pad_label_idx(z + 1, j, k);
      float Lp = (lp >= 0) ? img[lp] : 0.0f;
      unsigned im = (tmpm[o] != 0xFFFFu) ? (unsigned)tmpm[o]
                                         : (0x8000u | (Lm == 3.0f ? 1u : 0u));
      unsigned ip = (tmpp[o] != 0xFFFFu) ? (unsigned)tmpp[o]
                                         : (0x8000u | (Lp == 3.0f ? 1u : 0u));
      lsR[p]  = (unsigned)o | ((unsigned)(o >> 1) << 16);
      auxR[p] = im | (ip << 16);
      p++;
    }
    __syncthreads();
    cntR = (int)tot;
    __syncthreads();
  }

  // ---- prefill BOTH pr parities with the full red half (consts + init) ----
  for (int c = tid; c < HPL; c += NTHR) {
    int j = c / 33, m = c - 33 * j;
    int k = (m << 1) + ((z + j + 1) & 1);     // red positions of plane z
    float v = (float)P1[NJK * j + k];
    cstoref(&pr0[(size_t)z * HPL + c], v);
    cstoref(&pr1[(size_t)z * HPL + c], v);
  }
  __syncthreads();                         // drain prefill
  // ---- startup barrier (count-only, 16 lines) ----
  if (tid == 0)
    __hip_atomic_fetch_add(&ctrl[(128u + (unsigned)(bid & 15)) * 16u], 1ull,
                           __ATOMIC_RELAXED, __HIP_MEMORY_SCOPE_AGENT);
  if (tid < 16) {
    for (;;) {
      unsigned long long v = cloadu(&ctrl[(128u + (unsigned)tid) * 16u]);
      v += __shfl_xor(v, 1, 64);  v += __shfl_xor(v, 2, 64);
      v += __shfl_xor(v, 4, 64);  v += __shfl_xor(v, 8, 64);
      if (v >= (unsigned long long)NBLK) break;
      __builtin_amdgcn_s_sleep(1);
    }
  }
  __syncthreads();

  const double WOPT = 2.0 / (1.0 + 3.14159265358979323846 / 66.0);
  const int zmc  = (z >= 1) ? (z - 1) : 0;
  const int zpc  = (z <= NI - 2) ? (z + 1) : (NI - 1);
  const int zm2c = (z >= 2) ? (z - 2) : 0;
  const int zp2c = (z <= NI - 3) ? (z + 2) : (NI - 1);

  int itout = 0;
  double dvout = 0.0;

  for (int t = 1; t <= 555; ++t) {
    const float* __restrict__ prold = (t & 1) ? pr0 : pr1;  // pr[(t-1)&1]
    float* __restrict__ prcur       = (t & 1) ? pr1 : pr0;  // pr[t&1]

    // ---- start-of-iter: flag waits (z+-1, z+-2) || ring poll + stop ----
    if (t > 1) {
      const int g = t - 2;
      if (wid == 0 && lane < 4) {
        int d = (lane < 2) ? 1 : 2;
        int nb = z + ((lane & 1) ? d : -d);
        if (nb >= 0 && nb < NBLK) {
          while (cloadu(&ctrl[(276u + (unsigned)nb) * 16u])
                 < (unsigned long long)(t - 1))
            __builtin_amdgcn_s_sleep(1);
        }
      }
      if (g >= 1 && wid == 1 && lane < 16) {
        const int r = g & 7;
        const unsigned n = ((unsigned)g + 7u) >> 3;
        const unsigned long long t64 =
            ((unsigned long long)NBLK * n) << 44;
        unsigned long long v;
        for (;;) {
          v = cloadu(&ctrl[((unsigned)r * 16u + (unsigned)lane) * 16u]);
          v += __shfl_xor(v, 1, 64);  v += __shfl_xor(v, 2, 64);
          v += __shfl_xor(v, 4, 64);  v += __shfl_xor(v, 8, 64);
          if (v >= t64) break;
          __builtin_amdgcn_s_sleep(1);
        }
        if (lane == 0) {
          unsigned long long cum = v & MASK44;
          sh_dv = (double)(cum - prevs[r]) * (1.0 / 1048576.0);
          prevs[r] = cum;
        }
      }
      __syncthreads();
      if (g >= 1) {
        double dvg = sh_dv;
        if (!((dvg >= 0.05) && (g <= 500))) { itout = g; dvout = dvg; break; }
      }
    }

    // ---- stage channels into LDS: z+-1 full halves + z+-2 far entries,
    //      max MLP (all loads to registers, then all LDS writes) ----
    {
      const float* __restrict__ srcm = prold + (size_t)zmc * HPL;
      const float* __restrict__ srcp = prold + (size_t)zpc * HPL;
      const float* __restrict__ sm2  = prold + (size_t)zm2c * HPL;
      const float* __restrict__ sp2  = prold + (size_t)zp2c * HPL;
      const bool t130 = (tid < HPL - 4 * NTHR);   // 130 tail threads
      float a0, a1, a2, a3, a4 = 0, b0, b1, b2, b3, b4 = 0;
      float fm = 0, fp = 0, fm2 = 0, fp2 = 0;
      a0 = cloadf(&srcm[tid]);
      a1 = cloadf(&srcm[tid + NTHR]);
      a2 = cloadf(&srcm[tid + 2 * NTHR]);
      a3 = cloadf(&srcm[tid + 3 * NTHR]);
      if (t130) a4 = cloadf(&srcm[tid + 4 * NTHR]);
      b0 = cloadf(&srcp[tid]);
      b1 = cloadf(&srcp[tid + NTHR]);
      b2 = cloadf(&srcp[tid + 2 * NTHR]);
      b3 = cloadf(&srcp[tid + 3 * NTHR]);
      if (t130) b4 = cloadf(&srcp[tid + 4 * NTHR]);
      if (tid < nHm)        fm  = cloadf(&sm2[(int)hm[tid] >> 1]);
      if (tid + NTHR < nHm) fm2 = cloadf(&sm2[(int)hm[tid + NTHR] >> 1]);
      if (tid < nHp)        fp  = cloadf(&sp2[(int)hp[tid] >> 1]);
      if (tid + NTHR < nHp) fp2 = cloadf(&sp2[(int)hp[tid + NTHR] >> 1]);
      CM[tid] = a0; CM[tid + NTHR] = a1; CM[tid + 2 * NTHR] = a2;
      CM[tid + 3 * NTHR] = a3; if (t130) CM[tid + 4 * NTHR] = a4;
      CP[tid] = b0; CP[tid + NTHR] = b1; CP[tid + 2 * NTHR] = b2;
      CP[tid + 3 * NTHR] = b3; if (t130) CP[tid + 4 * NTHR] = b4;
      if (tid < nHm)        FM[tid] = fm;
      if (tid + NTHR < nHm) FM[tid + NTHR] = fm2;
      if (tid < nHp)        FP[tid] = fp;
      if (tid + NTHR < nHp) FP[tid + NTHR] = fp2;
    }
    __syncthreads();

    double acc = 0.0;
    // ====== BLACK own sweep (crosses from staged LDS) ======
    for (int p = tid; p < cntB; p += NTHR) {
      const unsigned u = lsB[p];
      const int o = (int)(u & 0xFFFFu);
      const int c = (int)(u >> 16);
      double fzm = (double)CM[c];
      double fzp = (double)CP[c];
      double xi = P1[o];
      double nb = ((((P1[o - 1] + P1[o + 1]) + P1[o - NJK]) + P1[o + NJK])
                  + fzm) + fzp;
      double adj = (WOPT * (nb - 6.0 * xi)) / 6.0;
      P1[o] = xi + adj;
      acc += fabs(adj);
    }
    // ====== halo-black updates (LDS only; disjoint from black sweep) ======
    for (int i = tid; i < nHm; i += NTHR) {
      const int o = (int)hm[i];
      const int c = o >> 1;
      double x = XBm[i];
      double nb = (((((double)CM[(o - 1) >> 1] + (double)CM[(o + 1) >> 1])
                    + (double)CM[c - 33]) + (double)CM[c + 33])
                    + (double)FM[i]) + P1[o];
      XBm[i] = x + (WOPT * (nb - 6.0 * x)) / 6.0;
    }
    for (int i = tid; i < nHp; i += NTHR) {
      const int o = (int)hp[i];
      const int c = o >> 1;
      double x = XBp[i];
      double nb = (((((double)CP[(o - 1) >> 1] + (double)CP[(o + 1) >> 1])
                    + (double)CP[c - 33]) + (double)CP[c + 33])
                    + P1[o]) + (double)FP[i];
      XBp[i] = x + (WOPT * (nb - 6.0 * x)) / 6.0;
    }
    __syncthreads();   // black P1 + XB visible

    // ====== RED own sweep: crosses from XB (LDS); inline publish ======
    {
      float* __restrict__ wpub = prcur + (size_t)z * HPL;
      for (int p = tid; p < cntR; p += NTHR) {
        const unsigned u = lsR[p];
        const int o = (int)(u & 0xFFFFu);
        const int c = (int)(u >> 16);
        const unsigned a2 = auxR[p];
        const unsigned im = a2 & 0xFFFFu, ip = a2 >> 16;
        double fzm = (im & 0x8000u) ? (double)(im & 1u) : XBm[im];
        double fzp = (ip & 0x8000u) ? (double)(ip & 1u) : XBp[ip];
        double xi = P1[o];
        double nb = ((((P1[o - 1] + P1[o + 1]) + P1[o - NJK]) + P1[o + NJK])
                    + fzm) + fzp;
        double adj = (WOPT * (nb - 6.0 * xi)) / 6.0;
        double v = xi + adj;
        P1[o] = v;
        cstoref(&wpub[c], (float)v);
        acc += fabs(adj);
      }
    }

    // ---- dv reduce (fixed order); FLAG FIRST, then ring post ----
    double a = acc;
    #pragma unroll
    for (int m = 32; m >= 1; m >>= 1) a += __shfl_xor(a, m, 64);
    if (lane == 0) redw[wid] = a;
    __syncthreads();                       // drains publishes; redw ready
    if (tid == 0) {
      cstoreu(&ctrl[(276u + (unsigned)bid) * 16u], (unsigned long long)t);
      double s = redw[0];
      #pragma unroll
      for (int w = 1; w < NW; ++w) s += redw[w];
      __hip_atomic_fetch_add(
          &ctrl[(((unsigned)t & 7u) * 16u + (unsigned)(bid & 15)) * 16u],
          CNT1 + (unsigned long long)(s * 1048576.0 + 0.5),
          __ATOMIC_RELAXED, __HIP_MEMORY_SCOPE_AGENT);
    }
  }

  // ---- epilogue: lap straight from LDS (crop pad), + iters + dv ----
  {
    const int vb = (z >= 66) ? 1 : 0;
    const int pz = z - 66 * vb;
    if (pz >= 1 && pz <= 64) {
      float* ob = out + ((size_t)vb * 64 + (pz - 1)) * 4096;
      for (int t2 = tid; t2 < 4096; t2 += NTHR) {
        int jj = t2 >> 6, kk = t2 & 63;
        ob[t2] = (float)P1[NJK * (jj + 1) + (kk + 1)];
      }
    }
    if (z == 0 && tid == 0) {
      out[NOUT]     = (float)itout;
      out[NOUT + 1] = (float)dvout;
    }
  }
}

extern "C" void kernel_launch(void* const* d_in, const int* in_sizes, int n_in,
                              void* d_out, int out_size, void* d_ws, size_t ws_size,
                              hipStream_t stream) {
  const float* img = (const float*)d_in[0];
  float* out = (float*)d_out;
  float* pr0 = (float*)d_ws;
  float* pr1 = pr0 + (size_t)NI * HPL;
  unsigned long long* ctrl = (unsigned long long*)(pr1 + (size_t)NI * HPL);

  sor_init_ctrl<<<1, 256, 0, stream>>>(ctrl);
  sor_main<<<NBLK, NTHR, 0, stream>>>(img, pr0, pr1, ctrl, out);
}